// Round 8
// baseline (117.280 us; speedup 1.0000x reference)
//
#include <hip/hip_runtime.h>

#define N_SENT 1024
#define LSEQ   128
#define HDIM   768
#define KSPAN  5
#define TPB    192   // HDIM / 4 float4 lanes
#define UNROLL 8
#define NITEMS (2 * N_SENT)
#define NBLOCKS NITEMS   // all resident (8 blocks/CU, 24 waves/CU), steal via counter

typedef float f32x4 __attribute__((ext_vector_type(4)));

__global__ __launch_bounds__(TPB) void bert_pool_kernel(
    const float* __restrict__ review_feat,   // [N, L, H]
    const float* __restrict__ reply_feat,    // [N, L, H]
    const int*   __restrict__ review_nt,     // [N]
    const int*   __restrict__ reply_nt,      // [N]
    const int*   __restrict__ review_ss,     // [N, K]
    const int*   __restrict__ review_se,     // [N, K]
    const int*   __restrict__ reply_ss,      // [N, K]
    const int*   __restrict__ reply_se,      // [N, K]
    float*       __restrict__ out,           // [4, N, H]
    int*         __restrict__ ctr)           // zeroed before launch
{
    const int tid = threadIdx.x;
    __shared__ int item_s;

    for (;;) {
        if (tid == 0) item_s = atomicAdd(ctr, 1);
        __syncthreads();
        const int item = item_s;
        __syncthreads();               // protect item_s before next store
        if (item >= NITEMS) return;

        const int  n        = item >> 1;          // interleaved: adjacent items alternate tensors
        const bool is_reply = (item & 1) != 0;

        const float* feat = is_reply ? reply_feat : review_feat;
        const int*   ntp  = is_reply ? reply_nt   : review_nt;
        const int*   ssp  = is_reply ? reply_ss   : review_ss;
        const int*   sep  = is_reply ? reply_se   : review_se;
        float* out_pt   = out + (is_reply ? 2 : 0) * (size_t)N_SENT * HDIM;
        float* out_sent = out + (is_reply ? 3 : 1) * (size_t)N_SENT * HDIM;

        const int nt = ntp[n];

        int s[KSPAN], e[KSPAN];
        int l_lo = 1, l_hi = nt;
#pragma unroll
        for (int k = 0; k < KSPAN; ++k) {
            s[k] = ssp[(size_t)n * KSPAN + k];
            e[k] = sep[(size_t)n * KSPAN + k];
            if (s[k] <= e[k]) {
                if (s[k] < l_lo) l_lo = s[k];
                if (e[k] > l_hi) l_hi = e[k];
            }
        }
        if (l_lo < 0) l_lo = 0;
        if (l_hi > LSEQ - 1) l_hi = LSEQ - 1;

        const f32x4* frow = (const f32x4*)(feat + (size_t)n * LSEQ * HDIM);

        float sx = 0.f, sy = 0.f, sz = 0.f, sw = 0.f;
        float px = 0.f, py = 0.f, pz = 0.f, pw = 0.f;
        float span_cnt = 0.f;

        const int rows      = l_hi - l_lo + 1;
        const int full_end  = l_lo + (rows / UNROLL) * UNROLL;   // exclusive

        // ---- full UNROLL groups: 8 NT loads in flight, no dead slots ----
        for (int l0 = l_lo; l0 < full_end; l0 += UNROLL) {
            f32x4 v[UNROLL];
            float ms[UNROLL], mp[UNROLL];
#pragma unroll
            for (int i = 0; i < UNROLL; ++i) {
                const int l = l0 + i;
                v[i] = __builtin_nontemporal_load(&frow[(size_t)l * (HDIM / 4) + tid]);
                ms[i] = (l >= 1 && l <= nt) ? 1.0f : 0.0f;
                bool insp = false;
#pragma unroll
                for (int k = 0; k < KSPAN; ++k)
                    insp = insp || ((l >= s[k]) && (l <= e[k]));
                mp[i] = insp ? 1.0f : 0.0f;
            }
#pragma unroll
            for (int i = 0; i < UNROLL; ++i) {
                sx = fmaf(v[i].x, ms[i], sx);
                sy = fmaf(v[i].y, ms[i], sy);
                sz = fmaf(v[i].z, ms[i], sz);
                sw = fmaf(v[i].w, ms[i], sw);
                px = fmaf(v[i].x, mp[i], px);
                py = fmaf(v[i].y, mp[i], py);
                pz = fmaf(v[i].z, mp[i], pz);
                pw = fmaf(v[i].w, mp[i], pw);
                span_cnt += mp[i];
            }
        }

        // ---- remainder (< UNROLL rows): plain loads, no duplicates ----
        for (int l = full_end; l <= l_hi; ++l) {
            f32x4 v = frow[(size_t)l * (HDIM / 4) + tid];
            const float msc = (l >= 1 && l <= nt) ? 1.0f : 0.0f;
            bool insp = false;
#pragma unroll
            for (int k = 0; k < KSPAN; ++k)
                insp = insp || ((l >= s[k]) && (l <= e[k]));
            const float mpc = insp ? 1.0f : 0.0f;
            sx = fmaf(v.x, msc, sx);
            sy = fmaf(v.y, msc, sy);
            sz = fmaf(v.z, msc, sz);
            sw = fmaf(v.w, msc, sw);
            px = fmaf(v.x, mpc, px);
            py = fmaf(v.y, mpc, py);
            pz = fmaf(v.z, mpc, pz);
            pw = fmaf(v.w, mpc, pw);
            span_cnt += mpc;
        }

        const float sent_cnt = (float)(nt < LSEQ - 1 ? nt : LSEQ - 1);
        const float inv_s = 1.0f / sent_cnt;
        const float smx = sx * inv_s, smy = sy * inv_s, smz = sz * inv_s, smw = sw * inv_s;

        const bool  has_span = (span_cnt > 0.5f);
        const float inv_p = 1.0f / fmaxf(span_cnt, 1.0f);
        const float ptx = has_span ? px * inv_p : smx;
        const float pty = has_span ? py * inv_p : smy;
        const float ptz = has_span ? pz * inv_p : smz;
        const float ptw = has_span ? pw * inv_p : smw;

        f32x4 rpt = {ptx, pty, ptz, ptw};
        f32x4 rsn = {smx, smy, smz, smw};
        __builtin_nontemporal_store(rpt, &((f32x4*)(out_pt   + (size_t)n * HDIM))[tid]);
        __builtin_nontemporal_store(rsn, &((f32x4*)(out_sent + (size_t)n * HDIM))[tid]);
    }
}

extern "C" void kernel_launch(void* const* d_in, const int* in_sizes, int n_in,
                              void* d_out, int out_size, void* d_ws, size_t ws_size,
                              hipStream_t stream) {
    const float* review_feat = (const float*)d_in[0];
    const float* reply_feat  = (const float*)d_in[1];
    const int*   review_nt   = (const int*)d_in[2];
    const int*   reply_nt    = (const int*)d_in[3];
    const int*   review_ss   = (const int*)d_in[4];
    const int*   review_se   = (const int*)d_in[5];
    const int*   reply_ss    = (const int*)d_in[6];
    const int*   reply_se    = (const int*)d_in[7];
    float* out = (float*)d_out;
    int*   ctr = (int*)d_ws;

    hipMemsetAsync(ctr, 0, sizeof(int), stream);
    bert_pool_kernel<<<NBLOCKS, TPB, 0, stream>>>(
        review_feat, reply_feat, review_nt, reply_nt,
        review_ss, review_se, reply_ss, reply_se, out, ctr);
}

// Round 9
// 90.280 us; speedup vs baseline: 1.2991x; 1.2991x over previous
//
#include <hip/hip_runtime.h>

#define N_SENT 1024
#define LSEQ   128
#define HDIM   768
#define KSPAN  5
#define TPB    192   // HDIM / 4 float4 lanes
#define G      6     // rows per pipeline group (double-buffered: 6-12 loads in flight)

typedef float f32x4 __attribute__((ext_vector_type(4)));

struct Acc {
    float sx, sy, sz, sw;   // sentence
    float px, py, pz, pw;   // span
    float cnt;
};

__device__ __forceinline__ void load_group(f32x4* v, const f32x4* frow, int l0, int tid) {
#pragma unroll
    for (int i = 0; i < G; ++i)
        v[i] = __builtin_nontemporal_load(&frow[(size_t)(l0 + i) * (HDIM / 4) + tid]);
}

__device__ __forceinline__ void consume_group(const f32x4* v, int l0, int nt,
                                              const int* s, const int* e, Acc& a) {
#pragma unroll
    for (int i = 0; i < G; ++i) {
        const int l = l0 + i;
        const float ms = (l >= 1 && l <= nt) ? 1.0f : 0.0f;
        bool insp = false;
#pragma unroll
        for (int k = 0; k < KSPAN; ++k)
            insp = insp || ((l >= s[k]) && (l <= e[k]));
        const float mp = insp ? 1.0f : 0.0f;
        a.sx = fmaf(v[i].x, ms, a.sx);
        a.sy = fmaf(v[i].y, ms, a.sy);
        a.sz = fmaf(v[i].z, ms, a.sz);
        a.sw = fmaf(v[i].w, ms, a.sw);
        a.px = fmaf(v[i].x, mp, a.px);
        a.py = fmaf(v[i].y, mp, a.py);
        a.pz = fmaf(v[i].z, mp, a.pz);
        a.pw = fmaf(v[i].w, mp, a.pw);
        a.cnt += mp;
    }
}

__global__ __launch_bounds__(TPB) void bert_pool_kernel(
    const float* __restrict__ review_feat,   // [N, L, H]
    const float* __restrict__ reply_feat,    // [N, L, H]
    const int*   __restrict__ review_nt,     // [N]
    const int*   __restrict__ reply_nt,      // [N]
    const int*   __restrict__ review_ss,     // [N, K]
    const int*   __restrict__ review_se,     // [N, K]
    const int*   __restrict__ reply_ss,      // [N, K]
    const int*   __restrict__ reply_se,      // [N, K]
    float*       __restrict__ out)           // [4, N, H]
{
    const int item = blockIdx.x;             // tensor-interleaved
    const int n    = item >> 1;
    const int tid  = threadIdx.x;
    const bool is_reply = (item & 1) != 0;

    const float* feat = is_reply ? reply_feat : review_feat;
    const int*   ntp  = is_reply ? reply_nt   : review_nt;
    const int*   ssp  = is_reply ? reply_ss   : review_ss;
    const int*   sep  = is_reply ? reply_se   : review_se;
    float* out_pt   = out + (is_reply ? 2 : 0) * (size_t)N_SENT * HDIM;
    float* out_sent = out + (is_reply ? 3 : 1) * (size_t)N_SENT * HDIM;

    const int nt = ntp[n];

    int s[KSPAN], e[KSPAN];
    int l_lo = 1, l_hi = nt;
#pragma unroll
    for (int k = 0; k < KSPAN; ++k) {
        s[k] = ssp[(size_t)n * KSPAN + k];
        e[k] = sep[(size_t)n * KSPAN + k];
        if (s[k] <= e[k]) {
            if (s[k] < l_lo) l_lo = s[k];
            if (e[k] > l_hi) l_hi = e[k];
        }
    }
    if (l_lo < 0) l_lo = 0;
    if (l_hi > LSEQ - 1) l_hi = LSEQ - 1;

    const f32x4* frow = (const f32x4*)(feat + (size_t)n * LSEQ * HDIM);

    Acc a = {0.f,0.f,0.f,0.f, 0.f,0.f,0.f,0.f, 0.f};

    const int rows = l_hi - l_lo + 1;
    const int ng   = rows / G;               // full groups

    // ---- software-pipelined double buffer: consume group g while g+1 in flight ----
    f32x4 vA[G], vB[G];
    int g = 0;
    if (ng > 0) load_group(vA, frow, l_lo, tid);
    while (g + 2 <= ng) {
        load_group(vB, frow, l_lo + (g + 1) * G, tid);
        consume_group(vA, l_lo + g * G, nt, s, e, a);
        if (g + 2 < ng) {
            load_group(vA, frow, l_lo + (g + 2) * G, tid);
            consume_group(vB, l_lo + (g + 1) * G, nt, s, e, a);
        } else {
            consume_group(vB, l_lo + (g + 1) * G, nt, s, e, a);
        }
        g += 2;
    }
    if (g < ng) {                            // odd group count: vA holds group g
        consume_group(vA, l_lo + g * G, nt, s, e, a);
        g++;
    }

    // ---- remainder rows (< G), NT loads, no duplicates ----
    for (int l = l_lo + ng * G; l <= l_hi; ++l) {
        f32x4 v = __builtin_nontemporal_load(&frow[(size_t)l * (HDIM / 4) + tid]);
        const float ms = (l >= 1 && l <= nt) ? 1.0f : 0.0f;
        bool insp = false;
#pragma unroll
        for (int k = 0; k < KSPAN; ++k)
            insp = insp || ((l >= s[k]) && (l <= e[k]));
        const float mp = insp ? 1.0f : 0.0f;
        a.sx = fmaf(v.x, ms, a.sx);
        a.sy = fmaf(v.y, ms, a.sy);
        a.sz = fmaf(v.z, ms, a.sz);
        a.sw = fmaf(v.w, ms, a.sw);
        a.px = fmaf(v.x, mp, a.px);
        a.py = fmaf(v.y, mp, a.py);
        a.pz = fmaf(v.z, mp, a.pz);
        a.pw = fmaf(v.w, mp, a.pw);
        a.cnt += mp;
    }

    const float sent_cnt = (float)(nt < LSEQ - 1 ? nt : LSEQ - 1);
    const float inv_s = 1.0f / sent_cnt;
    const float smx = a.sx * inv_s, smy = a.sy * inv_s, smz = a.sz * inv_s, smw = a.sw * inv_s;

    const bool  has_span = (a.cnt > 0.5f);
    const float inv_p = 1.0f / fmaxf(a.cnt, 1.0f);
    const float ptx = has_span ? a.px * inv_p : smx;
    const float pty = has_span ? a.py * inv_p : smy;
    const float ptz = has_span ? a.pz * inv_p : smz;
    const float ptw = has_span ? a.pw * inv_p : smw;

    f32x4 rpt = {ptx, pty, ptz, ptw};
    f32x4 rsn = {smx, smy, smz, smw};
    __builtin_nontemporal_store(rpt, &((f32x4*)(out_pt   + (size_t)n * HDIM))[tid]);
    __builtin_nontemporal_store(rsn, &((f32x4*)(out_sent + (size_t)n * HDIM))[tid]);
}

extern "C" void kernel_launch(void* const* d_in, const int* in_sizes, int n_in,
                              void* d_out, int out_size, void* d_ws, size_t ws_size,
                              hipStream_t stream) {
    const float* review_feat = (const float*)d_in[0];
    const float* reply_feat  = (const float*)d_in[1];
    const int*   review_nt   = (const int*)d_in[2];
    const int*   reply_nt    = (const int*)d_in[3];
    const int*   review_ss   = (const int*)d_in[4];
    const int*   review_se   = (const int*)d_in[5];
    const int*   reply_ss    = (const int*)d_in[6];
    const int*   reply_se    = (const int*)d_in[7];
    float* out = (float*)d_out;

    bert_pool_kernel<<<2 * N_SENT, TPB, 0, stream>>>(
        review_feat, reply_feat, review_nt, reply_nt,
        review_ss, review_se, reply_ss, reply_se, out);
}